// Round 9
// baseline (647.894 us; speedup 1.0000x reference)
//
#include <hip/hip_runtime.h>
#include <hip/hip_cooperative_groups.h>

namespace cg = cooperative_groups;

#define N_NODES 50000
#define N_EDGES 800000
#define IN_C 128
#define HID_C 128
#define OUT_C 64

// bucket CSR build (R2-verified parameters)
#define NBUCK 500
#define NODES_PER_BUCK 100
#define BCAP 2560
#define CURS_STRIDE 16   // one 64B line per bucket cursor
#define BA_CHUNK 4096    // probed optimum (2048=189.5, 4096=183.9, 8192=184.6)
#define BA_BLOCKS ((N_EDGES + BA_CHUNK - 1) / BA_CHUNK)  // 196

// prep virtual-block ranges
#define XB_BLOCKS 3125   // N_NODES*IN_C/(8*256) -- 32B per thread
#define W1T_BLOCKS 128
#define W2T_BLOCKS 64
#define PREP_BLOCKS (XB_BLOCKS + W1T_BLOCKS + W2T_BLOCKS)
#define NV_A (BA_BLOCKS + PREP_BLOCKS)   // phase-A virtual blocks

#define NTILES ((N_NODES + 127) / 128)   // 391 gemm tiles

#define LDK 72   // Bs stride
#define LDH 136  // As stride
#define SMEM_BYTES (128 * LDH * 2 + 128 * LDK * 2)  // 53248 B (max over phases)

typedef __bf16 bf16x8 __attribute__((ext_vector_type(8)));
typedef float  f32x4  __attribute__((ext_vector_type(4)));

// ============================================================================
// Monolithic cooperative kernel. R8 analysis: R2's 6 dependent launches carry
// ~75us of launch/drain gaps (kernels sum to ~105us of 183.9). One launch +
// 5 grid.sync()s removes them. Each phase body is the R2-verified code; only
// the wrappers (grid-stride loops, smem aliasing) are new.
// Phases: 0 zero cursor | A prep+bucketA | B bucketB | C agg_x | D gemm12 | E agg2
// ============================================================================
__global__ __launch_bounds__(256, 2) void mono_kernel(
    const float* __restrict__ x,
    const float* __restrict__ W1l, const float* __restrict__ W1r,
    const float* __restrict__ W2l, const float* __restrict__ W2r,
    const float* __restrict__ b1,  const float* __restrict__ b2,
    const int* __restrict__ src,   const int* __restrict__ dst,
    int* cursor, unsigned* ebuf, int* row_ptr, int* srcs,
    __bf16* xb, __bf16* W1T, __bf16* W2T, __bf16* m1,
    __bf16* Y, float* Z, float* out)
{
    cg::grid_group gridg = cg::this_grid();
    __shared__ __align__(16) char smem[SMEM_BYTES];
    const int tid = threadIdx.x;
    const int bid = blockIdx.x;
    const int nblk = gridDim.x;

    // ---- phase 0: zero bucket cursors ----
    for (int i = bid * 256 + tid; i < NBUCK * CURS_STRIDE; i += nblk * 256)
        cursor[i] = 0;
    __threadfence();
    gridg.sync();

    // ---- phase A: bucketA chunks (vb<BA_BLOCKS) + prep (xb/W1T/W2T) ----
    {
        int* cnt   = (int*)smem;
        int* gbase = cnt + NBUCK;
        int* lcur  = gbase + NBUCK;
        for (int vb = bid; vb < NV_A; vb += nblk) {
            if (vb < BA_BLOCKS) {
                for (int i = tid; i < NBUCK; i += 256) cnt[i] = 0;
                __syncthreads();
                const int e0 = vb * BA_CHUNK;
                const int e1 = (e0 + BA_CHUNK < N_EDGES) ? e0 + BA_CHUNK : N_EDGES;
                const int nE = e1 - e0;  // multiple of 4
                for (int q = 4 * tid; q + 3 < nE; q += 1024) {
                    int4 d4 = *(const int4*)(dst + e0 + q);
                    atomicAdd(&cnt[d4.x / NODES_PER_BUCK], 1);
                    atomicAdd(&cnt[d4.y / NODES_PER_BUCK], 1);
                    atomicAdd(&cnt[d4.z / NODES_PER_BUCK], 1);
                    atomicAdd(&cnt[d4.w / NODES_PER_BUCK], 1);
                }
                __syncthreads();
                for (int i = tid; i < NBUCK; i += 256) {
                    gbase[i] = i * BCAP + atomicAdd(&cursor[i * CURS_STRIDE], cnt[i]);
                    lcur[i] = 0;
                }
                __syncthreads();
                for (int q = 4 * tid; q + 3 < nE; q += 1024) {
                    int4 s4 = *(const int4*)(src + e0 + q);
                    int4 d4 = *(const int4*)(dst + e0 + q);
                    {
                        int d = d4.x, b = d / NODES_PER_BUCK;
                        int idx = gbase[b] + atomicAdd(&lcur[b], 1);
                        if (idx < (b + 1) * BCAP)
                            ebuf[idx] = (unsigned)s4.x | ((unsigned)(d - b * NODES_PER_BUCK) << 16);
                    }
                    {
                        int d = d4.y, b = d / NODES_PER_BUCK;
                        int idx = gbase[b] + atomicAdd(&lcur[b], 1);
                        if (idx < (b + 1) * BCAP)
                            ebuf[idx] = (unsigned)s4.y | ((unsigned)(d - b * NODES_PER_BUCK) << 16);
                    }
                    {
                        int d = d4.z, b = d / NODES_PER_BUCK;
                        int idx = gbase[b] + atomicAdd(&lcur[b], 1);
                        if (idx < (b + 1) * BCAP)
                            ebuf[idx] = (unsigned)s4.z | ((unsigned)(d - b * NODES_PER_BUCK) << 16);
                    }
                    {
                        int d = d4.w, b = d / NODES_PER_BUCK;
                        int idx = gbase[b] + atomicAdd(&lcur[b], 1);
                        if (idx < (b + 1) * BCAP)
                            ebuf[idx] = (unsigned)s4.w | ((unsigned)(d - b * NODES_PER_BUCK) << 16);
                    }
                }
                __syncthreads();  // protect cnt reuse by next virtual block
            } else {
                const int b = vb - BA_BLOCKS;
                if (b < XB_BLOCKS) {
                    int i = b * 256 + tid;
                    float4 v0 = ((const float4*)x)[2 * i];
                    float4 v1 = ((const float4*)x)[2 * i + 1];
                    bf16x8 o = { (__bf16)v0.x, (__bf16)v0.y, (__bf16)v0.z, (__bf16)v0.w,
                                 (__bf16)v1.x, (__bf16)v1.y, (__bf16)v1.z, (__bf16)v1.w };
                    ((bf16x8*)xb)[i] = o;
                } else if (b < XB_BLOCKS + W1T_BLOCKS) {
                    int i = (b - XB_BLOCKS) * 256 + tid;
                    int n = i >> 8, kk = i & 255;
                    float v = (kk < 128) ? W1l[kk * 128 + n] : W1r[(kk - 128) * 128 + n];
                    W1T[i] = (__bf16)v;
                } else {
                    int i = (b - XB_BLOCKS - W1T_BLOCKS) * 256 + tid;
                    int n = i >> 7, k = i & 127;
                    float v = (n < 64) ? W2l[k * 64 + n] : W2r[k * 64 + (n - 64)];
                    W2T[i] = (__bf16)v;
                }
            }
        }
    }
    __threadfence();
    gridg.sync();

    // ---- phase B: bucket CSR finalize ----
    {
        int* psum = (int*)smem;
        int* deg  = psum + 256;
        int* ofs  = deg + NODES_PER_BUCK;
        for (int vb = bid; vb < NBUCK; vb += nblk) {
            const int b = vb;
            int part = 0;
            for (int i = tid; i < b; i += 256) {
                int c = cursor[i * CURS_STRIDE];
                if (c > BCAP) c = BCAP;
                part += c;
            }
            psum[tid] = part;
            __syncthreads();
            for (int off = 128; off > 0; off >>= 1) {
                if (tid < off) psum[tid] += psum[tid + off];
                __syncthreads();
            }
            const int rbase = psum[0];
            int m = cursor[b * CURS_STRIDE];
            if (m > BCAP) m = BCAP;
            const int node0 = b * NODES_PER_BUCK;
            const unsigned* eb = ebuf + (size_t)b * BCAP;

            for (int i = tid; i < NODES_PER_BUCK; i += 256) deg[i] = 0;
            __syncthreads();
            for (int i = tid; i < m; i += 256)
                atomicAdd(&deg[eb[i] >> 16], 1);
            __syncthreads();
            if (tid == 0) {
                int s = 0;
                for (int i = 0; i < NODES_PER_BUCK; ++i) { ofs[i] = s; s += deg[i]; }
                ofs[NODES_PER_BUCK] = s;
            }
            __syncthreads();
            for (int i = tid; i < NODES_PER_BUCK; i += 256) row_ptr[node0 + i] = rbase + ofs[i];
            if (b == 0 && tid == 0) row_ptr[N_NODES] = N_EDGES;
            for (int i = tid; i < NODES_PER_BUCK; i += 256) deg[i] = ofs[i];
            __syncthreads();
            for (int i = tid; i < m; i += 256) {
                unsigned p = eb[i];
                int d = (int)(p >> 16);
                int pos = atomicAdd(&deg[d], 1);
                srcs[rbase + pos] = (int)(p & 0xFFFFu);
            }
            __syncthreads();  // protect psum/deg reuse by next virtual block
        }
    }
    __threadfence();
    gridg.sync();

    // ---- phase C: layer-1 aggregation m1 = mean(xb[src]) ----
    {
        const int wid = tid >> 6, lane = tid & 63;
        const int nwaves = nblk * 4;
        const int grp = lane >> 4;
        const int c   = lane & 15;
        for (int n = bid * 4 + wid; n < N_NODES; n += nwaves) {
            const int beg = row_ptr[n], end = row_ptr[n + 1];
            float acc[8] = {};
            int s = beg + grp;
            for (; s + 12 < end; s += 16) {
                int u0 = srcs[s];
                int u1 = srcs[s + 4];
                int u2 = srcs[s + 8];
                int u3 = srcs[s + 12];
                bf16x8 v0 = *(const bf16x8*)(xb + (size_t)u0 * 128 + c * 8);
                bf16x8 v1 = *(const bf16x8*)(xb + (size_t)u1 * 128 + c * 8);
                bf16x8 v2 = *(const bf16x8*)(xb + (size_t)u2 * 128 + c * 8);
                bf16x8 v3 = *(const bf16x8*)(xb + (size_t)u3 * 128 + c * 8);
#pragma unroll
                for (int j = 0; j < 8; j++) acc[j] += (float)v0[j];
#pragma unroll
                for (int j = 0; j < 8; j++) acc[j] += (float)v1[j];
#pragma unroll
                for (int j = 0; j < 8; j++) acc[j] += (float)v2[j];
#pragma unroll
                for (int j = 0; j < 8; j++) acc[j] += (float)v3[j];
            }
            for (; s < end; s += 4) {
                int u = srcs[s];
                bf16x8 v = *(const bf16x8*)(xb + (size_t)u * 128 + c * 8);
#pragma unroll
                for (int j = 0; j < 8; j++) acc[j] += (float)v[j];
            }
#pragma unroll
            for (int j = 0; j < 8; j++) {
                acc[j] += __shfl_xor(acc[j], 16, 64);
                acc[j] += __shfl_xor(acc[j], 32, 64);
            }
            float cnt = (float)(end - beg);
            if (cnt < 1.f) cnt = 1.f;
            if (grp == 0) {
                bf16x8 o;
#pragma unroll
                for (int j = 0; j < 8; j++) o[j] = (__bf16)(acc[j] / cnt);
                *(bf16x8*)(m1 + (size_t)n * 128 + c * 8) = o;
            }
        }
    }
    __threadfence();
    gridg.sync();

    // ---- phase D: fused GEMM1(+bias+relu)+GEMM2 over 391 tiles ----
    {
        __bf16* As = (__bf16*)smem;
        __bf16* Bs = (__bf16*)(smem + 128 * LDH * 2);
        const int wave = tid >> 6, lane = tid & 63;
        const int wm = (wave & 1) * 64, wn = (wave >> 1) * 64;
        const int lr = lane & 15, quad = lane >> 4;
        const int M = N_NODES;
        for (int vb = bid; vb < NTILES; vb += nblk) {
            const int row0 = vb * 128;

            // phase 1: K=256 over [m1|xb], 64-col rounds through As/Bs
            f32x4 acc[4][4] = {};
            for (int ks = 0; ks < 256; ks += 64) {
                const __bf16* Asrc = (ks < 128) ? m1 : xb;
                const int kofs = (ks < 128) ? ks : ks - 128;
                for (int i = tid; i < 128 * 8; i += 256) {
                    int r = i >> 3, ch = i & 7;
                    int gr = row0 + r;
                    float4 v = {0.f, 0.f, 0.f, 0.f};
                    if (gr < M) v = *(const float4*)(Asrc + (size_t)gr * 128 + kofs + ch * 8);
                    *(float4*)(As + r * LDH + ch * 8) = v;
                }
                for (int i = tid; i < 128 * 8; i += 256) {
                    int r = i >> 3, ch = i & 7;
                    float4 v = *(const float4*)(W1T + (size_t)r * 256 + ks + ch * 8);
                    *(float4*)(Bs + r * LDK + ch * 8) = v;
                }
                __syncthreads();
#pragma unroll
                for (int k0 = 0; k0 < 64; k0 += 32) {
                    bf16x8 af[4], bfr[4];
#pragma unroll
                    for (int mt = 0; mt < 4; mt++)
                        af[mt] = *(const bf16x8*)(As + (wm + mt * 16 + lr) * LDH + k0 + quad * 8);
#pragma unroll
                    for (int nt = 0; nt < 4; nt++)
                        bfr[nt] = *(const bf16x8*)(Bs + (wn + nt * 16 + lr) * LDK + k0 + quad * 8);
#pragma unroll
                    for (int mt = 0; mt < 4; mt++)
#pragma unroll
                        for (int nt = 0; nt < 4; nt++)
                            acc[mt][nt] = __builtin_amdgcn_mfma_f32_16x16x32_bf16(af[mt], bfr[nt], acc[mt][nt], 0, 0, 0);
                }
                __syncthreads();
            }

            // epilogue 1: h = relu(acc + b1) -> As (waves own disjoint quadrants)
#pragma unroll
            for (int mt = 0; mt < 4; mt++) {
#pragma unroll
                for (int r = 0; r < 4; r++) {
                    int row = wm + mt * 16 + quad * 4 + r;
#pragma unroll
                    for (int nt = 0; nt < 4; nt++) {
                        int col = wn + nt * 16 + lr;
                        float v = acc[mt][nt][r] + b1[col];
                        v = v > 0.f ? v : 0.f;
                        As[row * LDH + col] = (__bf16)v;
                    }
                }
            }

            // phase 2: K=128 over h, W2T in two 64-col rounds
            f32x4 acc2[4][4] = {};
            for (int kh = 0; kh < 128; kh += 64) {
                for (int i = tid; i < 128 * 8; i += 256) {
                    int r = i >> 3, ch = i & 7;
                    float4 v = *(const float4*)(W2T + (size_t)r * 128 + kh + ch * 8);
                    *(float4*)(Bs + r * LDK + ch * 8) = v;
                }
                __syncthreads();
#pragma unroll
                for (int k0 = 0; k0 < 64; k0 += 32) {
                    bf16x8 af[4], bfr[4];
#pragma unroll
                    for (int mt = 0; mt < 4; mt++)
                        af[mt] = *(const bf16x8*)(As + (wm + mt * 16 + lr) * LDH + kh + k0 + quad * 8);
#pragma unroll
                    for (int nt = 0; nt < 4; nt++)
                        bfr[nt] = *(const bf16x8*)(Bs + (wn + nt * 16 + lr) * LDK + k0 + quad * 8);
#pragma unroll
                    for (int mt = 0; mt < 4; mt++)
#pragma unroll
                        for (int nt = 0; nt < 4; nt++)
                            acc2[mt][nt] = __builtin_amdgcn_mfma_f32_16x16x32_bf16(af[mt], bfr[nt], acc2[mt][nt], 0, 0, 0);
                }
                __syncthreads();
            }

            // epilogue 2: Y bf16 / Z fp32
#pragma unroll
            for (int mt = 0; mt < 4; mt++) {
#pragma unroll
                for (int r = 0; r < 4; r++) {
                    int gr = row0 + wm + mt * 16 + quad * 4 + r;
                    if (gr >= M) continue;
#pragma unroll
                    for (int nt = 0; nt < 4; nt++) {
                        int gc = wn + nt * 16 + lr;
                        float v = acc2[mt][nt][r];
                        if (gc < 64) Y[(size_t)gr * 64 + gc] = (__bf16)v;
                        else         Z[(size_t)gr * 64 + (gc - 64)] = v;
                    }
                }
            }
            __syncthreads();  // protect As/Bs reuse by next tile
        }
    }
    __threadfence();
    gridg.sync();

    // ---- phase E: out = mean(Y[src]) + b2 + Z ----
    {
        const int wid = tid >> 6, lane = tid & 63;
        const int nwaves = nblk * 4;
        const int grp = lane >> 3;
        const int c   = lane & 7;
        for (int n = bid * 4 + wid; n < N_NODES; n += nwaves) {
            const int beg = row_ptr[n], end = row_ptr[n + 1];
            float4 z0 = {0,0,0,0}, z1 = {0,0,0,0}, bb0 = {0,0,0,0}, bb1 = {0,0,0,0};
            if (grp == 0) {
                z0 = *(const float4*)(Z + (size_t)n * 64 + c * 8);
                z1 = *(const float4*)(Z + (size_t)n * 64 + c * 8 + 4);
                bb0 = *(const float4*)(b2 + c * 8);
                bb1 = *(const float4*)(b2 + c * 8 + 4);
            }
            float acc[8] = {};
            int s = beg + grp;
            for (; s + 8 < end; s += 16) {
                int u0 = srcs[s];
                int u1 = srcs[s + 8];
                bf16x8 v0 = *(const bf16x8*)(Y + (size_t)u0 * 64 + c * 8);
                bf16x8 v1 = *(const bf16x8*)(Y + (size_t)u1 * 64 + c * 8);
#pragma unroll
                for (int j = 0; j < 8; j++) acc[j] += (float)v0[j];
#pragma unroll
                for (int j = 0; j < 8; j++) acc[j] += (float)v1[j];
            }
            if (s < end) {
                int u = srcs[s];
                bf16x8 v = *(const bf16x8*)(Y + (size_t)u * 64 + c * 8);
#pragma unroll
                for (int j = 0; j < 8; j++) acc[j] += (float)v[j];
            }
#pragma unroll
            for (int j = 0; j < 8; j++) {
                acc[j] += __shfl_xor(acc[j], 8, 64);
                acc[j] += __shfl_xor(acc[j], 16, 64);
                acc[j] += __shfl_xor(acc[j], 32, 64);
            }
            float cnt = (float)(end - beg);
            if (cnt < 1.f) cnt = 1.f;
            if (grp == 0) {
                float inv = 1.f / cnt;
                float4 o0 = { acc[0] * inv + bb0.x + z0.x, acc[1] * inv + bb0.y + z0.y,
                              acc[2] * inv + bb0.z + z0.z, acc[3] * inv + bb0.w + z0.w };
                float4 o1 = { acc[4] * inv + bb1.x + z1.x, acc[5] * inv + bb1.y + z1.y,
                              acc[6] * inv + bb1.z + z1.z, acc[7] * inv + bb1.w + z1.w };
                *(float4*)(out + (size_t)n * 64 + c * 8) = o0;
                *(float4*)(out + (size_t)n * 64 + c * 8 + 4) = o1;
            }
        }
    }
}

// ---------------- host ----------------

extern "C" void kernel_launch(void* const* d_in, const int* in_sizes, int n_in,
                              void* d_out, int out_size, void* d_ws, size_t ws_size,
                              hipStream_t stream) {
    const float* x   = (const float*)d_in[0];
    const int*   ei  = (const int*)d_in[1];
    const float* W1l = (const float*)d_in[2];
    const float* b1  = (const float*)d_in[3];
    const float* W1r = (const float*)d_in[4];
    const float* W2l = (const float*)d_in[5];
    const float* b2  = (const float*)d_in[6];
    const float* W2r = (const float*)d_in[7];
    float* out = (float*)d_out;

    // ---- workspace layout (~54 MB) with budget guard ----
    size_t need = 0;
    auto count = [&](size_t bytes) { need += (bytes + 255) & ~(size_t)255; };
    count((size_t)NBUCK * BCAP * 4);           // ebuf
    count((size_t)NBUCK * CURS_STRIDE * 4);    // cursor
    count((size_t)(N_NODES + 1) * 4);          // row_ptr
    count((size_t)N_EDGES * 4);                // srcs
    count((size_t)N_NODES * 128 * 2);          // xb
    count((size_t)128 * 256 * 2);              // W1T
    count((size_t)128 * 128 * 2);              // W2T
    count((size_t)N_NODES * 128 * 2);          // m1
    count((size_t)N_NODES * 64 * 2);           // Y
    count((size_t)N_NODES * 64 * 4);           // Z
    if (ws_size < need) return;

    char* ws = (char*)d_ws;
    size_t off = 0;
    auto alloc = [&](size_t bytes) -> void* {
        void* p = ws + off;
        off += (bytes + 255) & ~(size_t)255;
        return p;
    };
    unsigned* ebuf  = (unsigned*)alloc((size_t)NBUCK * BCAP * 4);
    int*    cursor  = (int*)alloc((size_t)NBUCK * CURS_STRIDE * 4);
    int*    row_ptr = (int*)alloc((size_t)(N_NODES + 1) * 4);
    int*    srcs    = (int*)alloc((size_t)N_EDGES * 4);
    __bf16* xb      = (__bf16*)alloc((size_t)N_NODES * 128 * 2);
    __bf16* W1T     = (__bf16*)alloc((size_t)128 * 256 * 2);
    __bf16* W2T     = (__bf16*)alloc((size_t)128 * 128 * 2);
    __bf16* m1      = (__bf16*)alloc((size_t)N_NODES * 128 * 2);
    __bf16* Y       = (__bf16*)alloc((size_t)N_NODES * 64 * 2);
    float*  Z       = (float*)alloc((size_t)N_NODES * 64 * 4);

    const int* src = ei;
    const int* dst = ei + N_EDGES;

    // grid = co-resident capacity (cooperative requirement); grid-stride
    // loops make any grid size correct. Target 2 blocks/CU (512 blocks).
    int nbpc = 0;
    hipOccupancyMaxActiveBlocksPerMultiprocessor(&nbpc, mono_kernel, 256, 0);
    if (nbpc < 1) return;
    int grid = (nbpc >= 2) ? 512 : 256;

    void* args[] = { (void*)&x, (void*)&W1l, (void*)&W1r, (void*)&W2l, (void*)&W2r,
                     (void*)&b1, (void*)&b2, (void*)&src, (void*)&dst,
                     (void*)&cursor, (void*)&ebuf, (void*)&row_ptr, (void*)&srcs,
                     (void*)&xb, (void*)&W1T, (void*)&W2T, (void*)&m1,
                     (void*)&Y, (void*)&Z, (void*)&out };
    hipLaunchCooperativeKernel((const void*)mono_kernel, dim3(grid), dim3(256),
                               args, 0, stream);
}

// Round 10
// 182.700 us; speedup vs baseline: 3.5462x; 3.5462x over previous
//
#include <hip/hip_runtime.h>

#define N_NODES 50000
#define N_EDGES 800000
#define IN_C 128
#define HID_C 128
#define OUT_C 64

// bucket CSR build
#define NBUCK 500        // 100 nodes per bucket
#define NODES_PER_BUCK 100
#define BCAP 2560        // capacity per bucket (mean 1600, sd ~40 -> +24 sd)
#define CURS_STRIDE 16   // cursor padded to one 64B line per bucket (atomic contention fix)
#define BA_CHUNK 4096    // edges per phase-A block (probed: 2048=189.5, 4096=183.9, 8192=184.6)
#define BA_BLOCKS ((N_EDGES + BA_CHUNK - 1) / BA_CHUNK)  // 196

// prep block ranges (fused kernel: bucketA blocks first, then prep blocks)
#define XB_BLOCKS 3125   // N_NODES*IN_C/(8*256) -- 32B per thread
#define W1T_BLOCKS 128   // 128*256/256
#define W2T_BLOCKS 64    // 128*128/256
#define PREP_BLOCKS (XB_BLOCKS + W1T_BLOCKS + W2T_BLOCKS)
#define FUSED_BLOCKS (BA_BLOCKS + PREP_BLOCKS)

typedef __bf16 bf16x8 __attribute__((ext_vector_type(8)));
typedef __bf16 bf16x4 __attribute__((ext_vector_type(4)));
typedef float  f32x4  __attribute__((ext_vector_type(4)));

// ---------------- fused prep + bucketA ----------------
// Blocks [0, BA_BLOCKS): edge histogram -> reservation -> packed placement.
// Blocks [BA_BLOCKS, FUSED_BLOCKS): xb convert + weight packs.
// cursor is ZERO-BASED and padded to 64B/bucket so reservation atomics from
// different blocks to different buckets never serialize on a shared cacheline.
// Reservation chain model (verified R1/R4/R5): ~30ns per same-line returning
// RMW at the coherence point, cost ~= BA_BLOCKS * 30ns.
// Structural lessons (measured): gathers need one-wave-per-node TLP (R8 -40,
// R9 -464 when violated); launch gaps are minor (R9 falsified the gap theory).
// ebuf entry: packed uint32 = src | (local_dst << 16); src < 50000 < 2^16.
__global__ __launch_bounds__(256) void prep_bucketA_kernel(const float* __restrict__ x,
                                                           const float* __restrict__ W1l,
                                                           const float* __restrict__ W1r,
                                                           const float* __restrict__ W2l,
                                                           const float* __restrict__ W2r,
                                                           __bf16* __restrict__ xb,
                                                           __bf16* __restrict__ W1T,
                                                           __bf16* __restrict__ W2T,
                                                           const int* __restrict__ src,
                                                           const int* __restrict__ dst,
                                                           int* __restrict__ cursor,
                                                           unsigned* __restrict__ ebuf) {
    __shared__ int cnt[NBUCK];
    __shared__ int gbase[NBUCK];
    __shared__ int lcur[NBUCK];
    const int blk = blockIdx.x, t = threadIdx.x;
    if (blk < BA_BLOCKS) {
        // ---- bucketA: critical path, dispatched first ----
        for (int i = t; i < NBUCK; i += 256) cnt[i] = 0;
        __syncthreads();
        const int e0 = blk * BA_CHUNK;
        const int e1 = (e0 + BA_CHUNK < N_EDGES) ? e0 + BA_CHUNK : N_EDGES;
        const int nE = e1 - e0;  // always divisible by 4
        for (int q = 4 * t; q + 3 < nE; q += 1024) {
            int4 d4 = *(const int4*)(dst + e0 + q);
            atomicAdd(&cnt[d4.x / NODES_PER_BUCK], 1);
            atomicAdd(&cnt[d4.y / NODES_PER_BUCK], 1);
            atomicAdd(&cnt[d4.z / NODES_PER_BUCK], 1);
            atomicAdd(&cnt[d4.w / NODES_PER_BUCK], 1);
        }
        __syncthreads();
        for (int i = t; i < NBUCK; i += 256) {
            // absolute base into ebuf; one 64B line per bucket cursor
            gbase[i] = i * BCAP + atomicAdd(&cursor[i * CURS_STRIDE], cnt[i]);
            lcur[i] = 0;
        }
        __syncthreads();
        for (int q = 4 * t; q + 3 < nE; q += 1024) {
            int4 s4 = *(const int4*)(src + e0 + q);
            int4 d4 = *(const int4*)(dst + e0 + q);
            {
                int d = d4.x, b = d / NODES_PER_BUCK;
                int idx = gbase[b] + atomicAdd(&lcur[b], 1);
                if (idx < (b + 1) * BCAP)
                    ebuf[idx] = (unsigned)s4.x | ((unsigned)(d - b * NODES_PER_BUCK) << 16);
            }
            {
                int d = d4.y, b = d / NODES_PER_BUCK;
                int idx = gbase[b] + atomicAdd(&lcur[b], 1);
                if (idx < (b + 1) * BCAP)
                    ebuf[idx] = (unsigned)s4.y | ((unsigned)(d - b * NODES_PER_BUCK) << 16);
            }
            {
                int d = d4.z, b = d / NODES_PER_BUCK;
                int idx = gbase[b] + atomicAdd(&lcur[b], 1);
                if (idx < (b + 1) * BCAP)
                    ebuf[idx] = (unsigned)s4.z | ((unsigned)(d - b * NODES_PER_BUCK) << 16);
            }
            {
                int d = d4.w, b = d / NODES_PER_BUCK;
                int idx = gbase[b] + atomicAdd(&lcur[b], 1);
                if (idx < (b + 1) * BCAP)
                    ebuf[idx] = (unsigned)s4.w | ((unsigned)(d - b * NODES_PER_BUCK) << 16);
            }
        }
        return;
    }
    const int b = blk - BA_BLOCKS;
    if (b < XB_BLOCKS) {
        int i = b * 256 + t;  // 8 floats -> 8 bf16 per thread
        float4 v0 = ((const float4*)x)[2 * i];
        float4 v1 = ((const float4*)x)[2 * i + 1];
        bf16x8 o = { (__bf16)v0.x, (__bf16)v0.y, (__bf16)v0.z, (__bf16)v0.w,
                     (__bf16)v1.x, (__bf16)v1.y, (__bf16)v1.z, (__bf16)v1.w };
        ((bf16x8*)xb)[i] = o;
    } else if (b < XB_BLOCKS + W1T_BLOCKS) {
        int i = (b - XB_BLOCKS) * 256 + t;
        int n = i >> 8, kk = i & 255;
        float v = (kk < 128) ? W1l[kk * 128 + n] : W1r[(kk - 128) * 128 + n];
        W1T[i] = (__bf16)v;
    } else {
        int i = (b - XB_BLOCKS - W1T_BLOCKS) * 256 + t;
        int n = i >> 7, k = i & 127;
        float v = (n < 64) ? W2l[k * 64 + n] : W2r[k * 64 + (n - 64)];
        W2T[i] = (__bf16)v;
    }
}

// Phase B: one block per bucket; computes its own global base from cursor
// (zero-based, padded stride); LDS count/scan over 100 nodes; emit row_ptr +
// place srcs into the block-exclusive contiguous output region.
__global__ __launch_bounds__(256) void bucketB_kernel(const unsigned* __restrict__ ebuf,
                                                      const int* __restrict__ cursor,
                                                      int* __restrict__ row_ptr,
                                                      int* __restrict__ srcs) {
    __shared__ int psum[256];
    __shared__ int deg[NODES_PER_BUCK];
    __shared__ int ofs[NODES_PER_BUCK + 1];
    const int b = blockIdx.x, t = threadIdx.x;
    // prefix over buckets < b (sizes clamped to BCAP)
    int part = 0;
    for (int i = t; i < b; i += 256) {
        int c = cursor[i * CURS_STRIDE];
        if (c > BCAP) c = BCAP;
        part += c;
    }
    psum[t] = part;
    __syncthreads();
    for (int off = 128; off > 0; off >>= 1) {
        if (t < off) psum[t] += psum[t + off];
        __syncthreads();
    }
    const int rbase = psum[0];
    int m = cursor[b * CURS_STRIDE];
    if (m > BCAP) m = BCAP;
    const int node0 = b * NODES_PER_BUCK;
    const unsigned* eb = ebuf + (size_t)b * BCAP;

    for (int i = t; i < NODES_PER_BUCK; i += 256) deg[i] = 0;
    __syncthreads();
    for (int i = t; i < m; i += 256)
        atomicAdd(&deg[eb[i] >> 16], 1);
    __syncthreads();
    if (t == 0) {
        int s = 0;
        for (int i = 0; i < NODES_PER_BUCK; ++i) { ofs[i] = s; s += deg[i]; }
        ofs[NODES_PER_BUCK] = s;
    }
    __syncthreads();
    for (int i = t; i < NODES_PER_BUCK; i += 256) row_ptr[node0 + i] = rbase + ofs[i];
    if (b == 0 && t == 0) row_ptr[N_NODES] = N_EDGES;
    for (int i = t; i < NODES_PER_BUCK; i += 256) deg[i] = ofs[i];  // reuse as cursors
    __syncthreads();
    for (int i = t; i < m; i += 256) {
        unsigned p = eb[i];
        int d = (int)(p >> 16);
        int pos = atomicAdd(&deg[d], 1);
        srcs[rbase + pos] = (int)(p & 0xFFFFu);
    }
}

// ---------------- layer 1 pre-aggregation: m1 = mean(xb[src]) (bf16) ----------------
// one wave per node (ESSENTIAL: 50000 waves of TLP — R8/R9 measured the cost
// of sequential multi-node waves); 16 lanes cover a 256B row; 4 lane-groups
// x 4-deep unroll -> 16 row-loads in flight per wave.
__global__ __launch_bounds__(256) void agg_x_kernel(const __bf16* __restrict__ xb,
                                                    const int* __restrict__ row_ptr,
                                                    const int* __restrict__ srcs,
                                                    __bf16* __restrict__ m1) {
    const int wid = threadIdx.x >> 6, lane = threadIdx.x & 63;
    const int n = blockIdx.x * 4 + wid;
    if (n >= N_NODES) return;
    const int beg = row_ptr[n], end = row_ptr[n + 1];
    const int grp = lane >> 4;   // edge slot 0..3
    const int c   = lane & 15;   // 16B chunk within row
    float acc[8] = {};
    int s = beg + grp;
    for (; s + 12 < end; s += 16) {
        int u0 = srcs[s];
        int u1 = srcs[s + 4];
        int u2 = srcs[s + 8];
        int u3 = srcs[s + 12];
        bf16x8 v0 = *(const bf16x8*)(xb + (size_t)u0 * 128 + c * 8);
        bf16x8 v1 = *(const bf16x8*)(xb + (size_t)u1 * 128 + c * 8);
        bf16x8 v2 = *(const bf16x8*)(xb + (size_t)u2 * 128 + c * 8);
        bf16x8 v3 = *(const bf16x8*)(xb + (size_t)u3 * 128 + c * 8);
#pragma unroll
        for (int j = 0; j < 8; j++) acc[j] += (float)v0[j];
#pragma unroll
        for (int j = 0; j < 8; j++) acc[j] += (float)v1[j];
#pragma unroll
        for (int j = 0; j < 8; j++) acc[j] += (float)v2[j];
#pragma unroll
        for (int j = 0; j < 8; j++) acc[j] += (float)v3[j];
    }
    for (; s < end; s += 4) {
        int u = srcs[s];
        bf16x8 v = *(const bf16x8*)(xb + (size_t)u * 128 + c * 8);
#pragma unroll
        for (int j = 0; j < 8; j++) acc[j] += (float)v[j];
    }
#pragma unroll
    for (int j = 0; j < 8; j++) {
        acc[j] += __shfl_xor(acc[j], 16, 64);
        acc[j] += __shfl_xor(acc[j], 32, 64);
    }
    float cnt = (float)(end - beg);
    if (cnt < 1.f) cnt = 1.f;
    if (grp == 0) {
        bf16x8 o;
#pragma unroll
        for (int j = 0; j < 8; j++) o[j] = (__bf16)(acc[j] / cnt);
        *(bf16x8*)(m1 + (size_t)n * 128 + c * 8) = o;
    }
}

// ---------------- fused GEMM1+GEMM2 ----------------
// Phase 1: h_tile = relu([m1|xb] @ W1T^T + b1)  -- kept in LDS (As, stride LDH)
// Phase 2: [Y|Z]  = h_tile @ W2T^T, staged in two K-halves through Bs (stride LDK)
// LDS: As 128x136 bf16 (34.8 KB) + Bs 128x72 (18.4 KB) = 53.2 KB
#define LDK 72   // Bs stride: 64-col staging tiles (+8 pad)
#define LDH 136  // As stride: fits the 128-col h tile (+8 pad), 16B-aligned rows

__global__ __launch_bounds__(256) void gemm12_kernel(const __bf16* __restrict__ A0,  // m1
                                                     const __bf16* __restrict__ A1,  // xb
                                                     const __bf16* __restrict__ W1T, // [128][256]
                                                     const __bf16* __restrict__ W2T, // [128][128]
                                                     const float* __restrict__ b1,
                                                     __bf16* __restrict__ Y,
                                                     float* __restrict__ Z, int M) {
    __shared__ __bf16 As[128 * LDH];
    __shared__ __bf16 Bs[128 * LDK];
    const int tid = threadIdx.x;
    const int row0 = blockIdx.x * 128;
    const int wave = tid >> 6, lane = tid & 63;
    const int wm = (wave & 1) * 64, wn = (wave >> 1) * 64;
    const int lr = lane & 15, quad = lane >> 4;

    // ---- phase 1: K=256 over [m1|xb] ----
    f32x4 acc[4][4] = {};
    for (int ks = 0; ks < 256; ks += 64) {
        const __bf16* Asrc = (ks < 128) ? A0 : A1;
        const int kofs = (ks < 128) ? ks : ks - 128;
        for (int i = tid; i < 128 * 8; i += 256) {
            int r = i >> 3, ch = i & 7;
            int gr = row0 + r;
            float4 v = {0.f, 0.f, 0.f, 0.f};
            if (gr < M) v = *(const float4*)(Asrc + (size_t)gr * 128 + kofs + ch * 8);
            *(float4*)(As + r * LDH + ch * 8) = v;
        }
        for (int i = tid; i < 128 * 8; i += 256) {
            int r = i >> 3, ch = i & 7;
            float4 v = *(const float4*)(W1T + (size_t)r * 256 + ks + ch * 8);
            *(float4*)(Bs + r * LDK + ch * 8) = v;
        }
        __syncthreads();
#pragma unroll
        for (int k0 = 0; k0 < 64; k0 += 32) {
            bf16x8 af[4], bfr[4];
#pragma unroll
            for (int mt = 0; mt < 4; mt++)
                af[mt] = *(const bf16x8*)(As + (wm + mt * 16 + lr) * LDH + k0 + quad * 8);
#pragma unroll
            for (int nt = 0; nt < 4; nt++)
                bfr[nt] = *(const bf16x8*)(Bs + (wn + nt * 16 + lr) * LDK + k0 + quad * 8);
#pragma unroll
            for (int mt = 0; mt < 4; mt++)
#pragma unroll
                for (int nt = 0; nt < 4; nt++)
                    acc[mt][nt] = __builtin_amdgcn_mfma_f32_16x16x32_bf16(af[mt], bfr[nt], acc[mt][nt], 0, 0, 0);
        }
        __syncthreads();
    }

    // ---- epilogue 1: h tile into As at stride LDH (bias+relu+bf16) ----
    // C/D layout: col = lane&15, row = quad*4 + reg. Waves write disjoint
    // 64x64 quadrants; the barrier inside the phase-2 loop orders reads.
#pragma unroll
    for (int mt = 0; mt < 4; mt++) {
#pragma unroll
        for (int r = 0; r < 4; r++) {
            int row = wm + mt * 16 + quad * 4 + r;
#pragma unroll
            for (int nt = 0; nt < 4; nt++) {
                int col = wn + nt * 16 + lr;
                float v = acc[mt][nt][r] + b1[col];
                v = v > 0.f ? v : 0.f;
                As[row * LDH + col] = (__bf16)v;
            }
        }
    }

    // ---- phase 2: K=128 over h tile, W2T staged in two 64-col halves ----
    f32x4 acc2[4][4] = {};
    for (int kh = 0; kh < 128; kh += 64) {
        for (int i = tid; i < 128 * 8; i += 256) {
            int r = i >> 3, ch = i & 7;
            float4 v = *(const float4*)(W2T + (size_t)r * 128 + kh + ch * 8);
            *(float4*)(Bs + r * LDK + ch * 8) = v;
        }
        __syncthreads();
#pragma unroll
        for (int k0 = 0; k0 < 64; k0 += 32) {
            bf16x8 af[4], bfr[4];
#pragma unroll
            for (int mt = 0; mt < 4; mt++)
                af[mt] = *(const bf16x8*)(As + (wm + mt * 16 + lr) * LDH + kh + k0 + quad * 8);
#pragma unroll
            for (int nt = 0; nt < 4; nt++)
                bfr[nt] = *(const bf16x8*)(Bs + (wn + nt * 16 + lr) * LDK + k0 + quad * 8);
#pragma unroll
            for (int mt = 0; mt < 4; mt++)
#pragma unroll
                for (int nt = 0; nt < 4; nt++)
                    acc2[mt][nt] = __builtin_amdgcn_mfma_f32_16x16x32_bf16(af[mt], bfr[nt], acc2[mt][nt], 0, 0, 0);
        }
        __syncthreads();
    }

    // ---- epilogue 2: Y bf16 / Z fp32 ----
#pragma unroll
    for (int mt = 0; mt < 4; mt++) {
#pragma unroll
        for (int r = 0; r < 4; r++) {
            int gr = row0 + wm + mt * 16 + quad * 4 + r;
            if (gr >= M) continue;
#pragma unroll
            for (int nt = 0; nt < 4; nt++) {
                int gc = wn + nt * 16 + lr;
                float v = acc2[mt][nt][r];
                if (gc < 64) Y[(size_t)gr * 64 + gc] = (__bf16)v;
                else         Z[(size_t)gr * 64 + (gc - 64)] = v;
            }
        }
    }
}

// ---------------- layer 2 aggregate + combine: out = mean(Y[src]) + b2 + Z ----------------
// one wave per node; 8 lanes cover a 128B Y row; 8 lane-groups x 2-deep
// unroll -> 16 loads in flight. Z/b2 loads hoisted to overlap latency.
__global__ __launch_bounds__(256) void agg2_kernel(const __bf16* __restrict__ Y,
                                                   const float* __restrict__ Z,
                                                   const int* __restrict__ row_ptr,
                                                   const int* __restrict__ srcs,
                                                   const float* __restrict__ b2,
                                                   float* __restrict__ out) {
    const int wid = threadIdx.x >> 6, lane = threadIdx.x & 63;
    const int n = blockIdx.x * 4 + wid;
    if (n >= N_NODES) return;
    const int beg = row_ptr[n], end = row_ptr[n + 1];
    const int grp = lane >> 3;  // edge slot 0..7
    const int c   = lane & 7;   // 16B chunk within row
    // hoist tail operands (only grp 0 consumes them)
    float4 z0 = {0,0,0,0}, z1 = {0,0,0,0}, bb0 = {0,0,0,0}, bb1 = {0,0,0,0};
    if (grp == 0) {
        z0 = *(const float4*)(Z + (size_t)n * 64 + c * 8);
        z1 = *(const float4*)(Z + (size_t)n * 64 + c * 8 + 4);
        bb0 = *(const float4*)(b2 + c * 8);
        bb1 = *(const float4*)(b2 + c * 8 + 4);
    }
    float acc[8] = {};
    int s = beg + grp;
    for (; s + 8 < end; s += 16) {
        int u0 = srcs[s];
        int u1 = srcs[s + 8];
        bf16x8 v0 = *(const bf16x8*)(Y + (size_t)u0 * 64 + c * 8);
        bf16x8 v1 = *(const bf16x8*)(Y + (size_t)u1 * 64 + c * 8);
#pragma unroll
        for (int j = 0; j < 8; j++) acc[j] += (float)v0[j];
#pragma unroll
        for (int j = 0; j < 8; j++) acc[j] += (float)v1[j];
    }
    if (s < end) {
        int u = srcs[s];
        bf16x8 v = *(const bf16x8*)(Y + (size_t)u * 64 + c * 8);
#pragma unroll
        for (int j = 0; j < 8; j++) acc[j] += (float)v[j];
    }
#pragma unroll
    for (int j = 0; j < 8; j++) {
        acc[j] += __shfl_xor(acc[j], 8, 64);
        acc[j] += __shfl_xor(acc[j], 16, 64);
        acc[j] += __shfl_xor(acc[j], 32, 64);
    }
    float cnt = (float)(end - beg);
    if (cnt < 1.f) cnt = 1.f;
    if (grp == 0) {
        float inv = 1.f / cnt;
        float4 o0 = { acc[0] * inv + bb0.x + z0.x, acc[1] * inv + bb0.y + z0.y,
                      acc[2] * inv + bb0.z + z0.z, acc[3] * inv + bb0.w + z0.w };
        float4 o1 = { acc[4] * inv + bb1.x + z1.x, acc[5] * inv + bb1.y + z1.y,
                      acc[6] * inv + bb1.z + z1.z, acc[7] * inv + bb1.w + z1.w };
        *(float4*)(out + (size_t)n * 64 + c * 8) = o0;
        *(float4*)(out + (size_t)n * 64 + c * 8 + 4) = o1;
    }
}

// ---------------- host ----------------

extern "C" void kernel_launch(void* const* d_in, const int* in_sizes, int n_in,
                              void* d_out, int out_size, void* d_ws, size_t ws_size,
                              hipStream_t stream) {
    const float* x   = (const float*)d_in[0];
    const int*   ei  = (const int*)d_in[1];
    const float* W1l = (const float*)d_in[2];
    const float* b1  = (const float*)d_in[3];
    const float* W1r = (const float*)d_in[4];
    const float* W2l = (const float*)d_in[5];
    const float* b2  = (const float*)d_in[6];
    const float* W2r = (const float*)d_in[7];
    float* out = (float*)d_out;

    // ---- workspace layout (~54 MB) with budget guard ----
    size_t need = 0;
    auto count = [&](size_t bytes) { need += (bytes + 255) & ~(size_t)255; };
    count((size_t)NBUCK * BCAP * 4);           // ebuf (packed uint32)
    count((size_t)NBUCK * CURS_STRIDE * 4);    // cursor (64B-padded)
    count((size_t)(N_NODES + 1) * 4);          // row_ptr
    count((size_t)N_EDGES * 4);                // srcs
    count((size_t)N_NODES * 128 * 2);          // xb
    count((size_t)128 * 256 * 2);              // W1T
    count((size_t)128 * 128 * 2);              // W2T
    count((size_t)N_NODES * 128 * 2);          // m1
    count((size_t)N_NODES * 64 * 2);           // Y
    count((size_t)N_NODES * 64 * 4);           // Z
    if (ws_size < need) return;

    char* ws = (char*)d_ws;
    size_t off = 0;
    auto alloc = [&](size_t bytes) -> void* {
        void* p = ws + off;
        off += (bytes + 255) & ~(size_t)255;
        return p;
    };
    unsigned* ebuf  = (unsigned*)alloc((size_t)NBUCK * BCAP * 4);
    int*    cursor  = (int*)alloc((size_t)NBUCK * CURS_STRIDE * 4);
    int*    row_ptr = (int*)alloc((size_t)(N_NODES + 1) * 4);
    int*    srcs    = (int*)alloc((size_t)N_EDGES * 4);
    __bf16* xb      = (__bf16*)alloc((size_t)N_NODES * 128 * 2);
    __bf16* W1T     = (__bf16*)alloc((size_t)128 * 256 * 2);
    __bf16* W2T     = (__bf16*)alloc((size_t)128 * 128 * 2);
    __bf16* m1      = (__bf16*)alloc((size_t)N_NODES * 128 * 2);
    __bf16* Y       = (__bf16*)alloc((size_t)N_NODES * 64 * 2);
    float*  Z       = (float*)alloc((size_t)N_NODES * 64 * 4);

    const int* src = ei;
    const int* dst = ei + N_EDGES;

    // 0. zero-init cursor (zero-based bucket counts; graph-capture-safe)
    hipMemsetAsync(cursor, 0, (size_t)NBUCK * CURS_STRIDE * 4, stream);
    // 1. fused prep + bucketA (bucketA blocks first: they feed the critical path)
    prep_bucketA_kernel<<<FUSED_BLOCKS, 256, 0, stream>>>(x, W1l, W1r, W2l, W2r,
                                                          xb, W1T, W2T,
                                                          src, dst, cursor, ebuf);
    // 2. bucket CSR finalize
    bucketB_kernel<<<NBUCK, 256, 0, stream>>>(ebuf, cursor, row_ptr, srcs);
    // 3. layer-1 pre-aggregation
    agg_x_kernel<<<(N_NODES + 3) / 4, 256, 0, stream>>>(xb, row_ptr, srcs, m1);
    // 4. fused GEMM1(+bias+relu)+GEMM2
    gemm12_kernel<<<(N_NODES + 127) / 128, 256, 0, stream>>>(m1, xb, W1T, W2T, b1, Y, Z, N_NODES);
    // 5. layer-2 aggregate + combine
    agg2_kernel<<<(N_NODES + 3) / 4, 256, 0, stream>>>(Y, Z, row_ptr, srcs, b2, out);
}

// Round 11
// 182.573 us; speedup vs baseline: 3.5487x; 1.0007x over previous
//
#include <hip/hip_runtime.h>

#define N_NODES 50000
#define N_EDGES 800000
#define IN_C 128
#define HID_C 128
#define OUT_C 64

// bucket CSR build
#define NBUCK 500        // 100 nodes per bucket
#define NODES_PER_BUCK 100
#define BCAP 2560        // capacity per bucket (mean 1600, sd ~40 -> +24 sd)
#define CURS_STRIDE 16   // cursor padded to one 64B line per bucket (atomic contention fix)
// R10 probe: decouple reservation-chain length from TLP. 8192-chunk (98 blocks
// -> ~3us chain) at 512 threads/block (784 waves, same TLP as 4096/256t).
#define BA_CHUNK 8192
#define BA_BLOCKS ((N_EDGES + BA_CHUNK - 1) / BA_CHUNK)  // 98
#define PB_THREADS 512

// prep block ranges (512-thread blocks)
#define XB_CHUNKS (N_NODES * IN_C / 8)                   // 800000 bf16x8 chunks
#define XB_BLOCKS ((XB_CHUNKS + PB_THREADS - 1) / PB_THREADS)  // 1563 (last partial)
#define W1T_BLOCKS (128 * 256 / PB_THREADS)              // 64
#define W2T_BLOCKS (128 * 128 / PB_THREADS)              // 32
#define PREP_BLOCKS (XB_BLOCKS + W1T_BLOCKS + W2T_BLOCKS)
#define FUSED_BLOCKS (BA_BLOCKS + PREP_BLOCKS)

typedef __bf16 bf16x8 __attribute__((ext_vector_type(8)));
typedef __bf16 bf16x4 __attribute__((ext_vector_type(4)));
typedef float  f32x4  __attribute__((ext_vector_type(4)));

// ---------------- fused prep + bucketA (512 threads) ----------------
// Blocks [0, BA_BLOCKS): edge histogram -> reservation -> packed placement.
// Blocks [BA_BLOCKS, FUSED_BLOCKS): xb convert + weight packs.
// cursor is ZERO-BASED and padded to 64B/bucket. Reservation chain model
// (verified R1/R4/R5): ~30ns per same-line returning RMW at the coherence
// point, cost ~= BA_BLOCKS * 30ns -> 98 blocks ~= 3us (vs 196 -> 6us).
// Structural lessons (measured): gathers need one-wave-per-node TLP (R8 -40,
// R9 -464 when violated); launch gaps are minor (R9 falsified the gap theory).
// ebuf entry: packed uint32 = src | (local_dst << 16); src < 50000 < 2^16.
__global__ __launch_bounds__(PB_THREADS) void prep_bucketA_kernel(const float* __restrict__ x,
                                                                  const float* __restrict__ W1l,
                                                                  const float* __restrict__ W1r,
                                                                  const float* __restrict__ W2l,
                                                                  const float* __restrict__ W2r,
                                                                  __bf16* __restrict__ xb,
                                                                  __bf16* __restrict__ W1T,
                                                                  __bf16* __restrict__ W2T,
                                                                  const int* __restrict__ src,
                                                                  const int* __restrict__ dst,
                                                                  int* __restrict__ cursor,
                                                                  unsigned* __restrict__ ebuf) {
    __shared__ int cnt[NBUCK];
    __shared__ int gbase[NBUCK];
    __shared__ int lcur[NBUCK];
    const int blk = blockIdx.x, t = threadIdx.x;
    if (blk < BA_BLOCKS) {
        // ---- bucketA: critical path, dispatched first ----
        for (int i = t; i < NBUCK; i += PB_THREADS) cnt[i] = 0;
        __syncthreads();
        const int e0 = blk * BA_CHUNK;
        const int e1 = (e0 + BA_CHUNK < N_EDGES) ? e0 + BA_CHUNK : N_EDGES;
        const int nE = e1 - e0;  // 8192 or 5376; always divisible by 4
        for (int q = 4 * t; q + 3 < nE; q += 4 * PB_THREADS) {
            int4 d4 = *(const int4*)(dst + e0 + q);
            atomicAdd(&cnt[d4.x / NODES_PER_BUCK], 1);
            atomicAdd(&cnt[d4.y / NODES_PER_BUCK], 1);
            atomicAdd(&cnt[d4.z / NODES_PER_BUCK], 1);
            atomicAdd(&cnt[d4.w / NODES_PER_BUCK], 1);
        }
        __syncthreads();
        for (int i = t; i < NBUCK; i += PB_THREADS) {
            // absolute base into ebuf; one 64B line per bucket cursor
            gbase[i] = i * BCAP + atomicAdd(&cursor[i * CURS_STRIDE], cnt[i]);
            lcur[i] = 0;
        }
        __syncthreads();
        for (int q = 4 * t; q + 3 < nE; q += 4 * PB_THREADS) {
            int4 s4 = *(const int4*)(src + e0 + q);
            int4 d4 = *(const int4*)(dst + e0 + q);
            {
                int d = d4.x, b = d / NODES_PER_BUCK;
                int idx = gbase[b] + atomicAdd(&lcur[b], 1);
                if (idx < (b + 1) * BCAP)
                    ebuf[idx] = (unsigned)s4.x | ((unsigned)(d - b * NODES_PER_BUCK) << 16);
            }
            {
                int d = d4.y, b = d / NODES_PER_BUCK;
                int idx = gbase[b] + atomicAdd(&lcur[b], 1);
                if (idx < (b + 1) * BCAP)
                    ebuf[idx] = (unsigned)s4.y | ((unsigned)(d - b * NODES_PER_BUCK) << 16);
            }
            {
                int d = d4.z, b = d / NODES_PER_BUCK;
                int idx = gbase[b] + atomicAdd(&lcur[b], 1);
                if (idx < (b + 1) * BCAP)
                    ebuf[idx] = (unsigned)s4.z | ((unsigned)(d - b * NODES_PER_BUCK) << 16);
            }
            {
                int d = d4.w, b = d / NODES_PER_BUCK;
                int idx = gbase[b] + atomicAdd(&lcur[b], 1);
                if (idx < (b + 1) * BCAP)
                    ebuf[idx] = (unsigned)s4.w | ((unsigned)(d - b * NODES_PER_BUCK) << 16);
            }
        }
        return;
    }
    const int b = blk - BA_BLOCKS;
    if (b < XB_BLOCKS) {
        int i = b * PB_THREADS + t;  // 8 floats -> 8 bf16 per thread
        if (i < XB_CHUNKS) {
            float4 v0 = ((const float4*)x)[2 * i];
            float4 v1 = ((const float4*)x)[2 * i + 1];
            bf16x8 o = { (__bf16)v0.x, (__bf16)v0.y, (__bf16)v0.z, (__bf16)v0.w,
                         (__bf16)v1.x, (__bf16)v1.y, (__bf16)v1.z, (__bf16)v1.w };
            ((bf16x8*)xb)[i] = o;
        }
    } else if (b < XB_BLOCKS + W1T_BLOCKS) {
        int i = (b - XB_BLOCKS) * PB_THREADS + t;
        int n = i >> 8, kk = i & 255;
        float v = (kk < 128) ? W1l[kk * 128 + n] : W1r[(kk - 128) * 128 + n];
        W1T[i] = (__bf16)v;
    } else {
        int i = (b - XB_BLOCKS - W1T_BLOCKS) * PB_THREADS + t;
        int n = i >> 7, k = i & 127;
        float v = (n < 64) ? W2l[k * 64 + n] : W2r[k * 64 + (n - 64)];
        W2T[i] = (__bf16)v;
    }
}

// Phase B: one block per bucket; computes its own global base from cursor
// (zero-based, padded stride); LDS count/scan over 100 nodes; emit row_ptr +
// place srcs into the block-exclusive contiguous output region.
__global__ __launch_bounds__(256) void bucketB_kernel(const unsigned* __restrict__ ebuf,
                                                      const int* __restrict__ cursor,
                                                      int* __restrict__ row_ptr,
                                                      int* __restrict__ srcs) {
    __shared__ int psum[256];
    __shared__ int deg[NODES_PER_BUCK];
    __shared__ int ofs[NODES_PER_BUCK + 1];
    const int b = blockIdx.x, t = threadIdx.x;
    // prefix over buckets < b (sizes clamped to BCAP)
    int part = 0;
    for (int i = t; i < b; i += 256) {
        int c = cursor[i * CURS_STRIDE];
        if (c > BCAP) c = BCAP;
        part += c;
    }
    psum[t] = part;
    __syncthreads();
    for (int off = 128; off > 0; off >>= 1) {
        if (t < off) psum[t] += psum[t + off];
        __syncthreads();
    }
    const int rbase = psum[0];
    int m = cursor[b * CURS_STRIDE];
    if (m > BCAP) m = BCAP;
    const int node0 = b * NODES_PER_BUCK;
    const unsigned* eb = ebuf + (size_t)b * BCAP;

    for (int i = t; i < NODES_PER_BUCK; i += 256) deg[i] = 0;
    __syncthreads();
    for (int i = t; i < m; i += 256)
        atomicAdd(&deg[eb[i] >> 16], 1);
    __syncthreads();
    if (t == 0) {
        int s = 0;
        for (int i = 0; i < NODES_PER_BUCK; ++i) { ofs[i] = s; s += deg[i]; }
        ofs[NODES_PER_BUCK] = s;
    }
    __syncthreads();
    for (int i = t; i < NODES_PER_BUCK; i += 256) row_ptr[node0 + i] = rbase + ofs[i];
    if (b == 0 && t == 0) row_ptr[N_NODES] = N_EDGES;
    for (int i = t; i < NODES_PER_BUCK; i += 256) deg[i] = ofs[i];  // reuse as cursors
    __syncthreads();
    for (int i = t; i < m; i += 256) {
        unsigned p = eb[i];
        int d = (int)(p >> 16);
        int pos = atomicAdd(&deg[d], 1);
        srcs[rbase + pos] = (int)(p & 0xFFFFu);
    }
}

// ---------------- layer 1 pre-aggregation: m1 = mean(xb[src]) (bf16) ----------------
// one wave per node (ESSENTIAL: 50000 waves of TLP — R8/R9 measured the cost
// of sequential multi-node waves); 16 lanes cover a 256B row; 4 lane-groups
// x 4-deep unroll -> 16 row-loads in flight per wave.
__global__ __launch_bounds__(256) void agg_x_kernel(const __bf16* __restrict__ xb,
                                                    const int* __restrict__ row_ptr,
                                                    const int* __restrict__ srcs,
                                                    __bf16* __restrict__ m1) {
    const int wid = threadIdx.x >> 6, lane = threadIdx.x & 63;
    const int n = blockIdx.x * 4 + wid;
    if (n >= N_NODES) return;
    const int beg = row_ptr[n], end = row_ptr[n + 1];
    const int grp = lane >> 4;   // edge slot 0..3
    const int c   = lane & 15;   // 16B chunk within row
    float acc[8] = {};
    int s = beg + grp;
    for (; s + 12 < end; s += 16) {
        int u0 = srcs[s];
        int u1 = srcs[s + 4];
        int u2 = srcs[s + 8];
        int u3 = srcs[s + 12];
        bf16x8 v0 = *(const bf16x8*)(xb + (size_t)u0 * 128 + c * 8);
        bf16x8 v1 = *(const bf16x8*)(xb + (size_t)u1 * 128 + c * 8);
        bf16x8 v2 = *(const bf16x8*)(xb + (size_t)u2 * 128 + c * 8);
        bf16x8 v3 = *(const bf16x8*)(xb + (size_t)u3 * 128 + c * 8);
#pragma unroll
        for (int j = 0; j < 8; j++) acc[j] += (float)v0[j];
#pragma unroll
        for (int j = 0; j < 8; j++) acc[j] += (float)v1[j];
#pragma unroll
        for (int j = 0; j < 8; j++) acc[j] += (float)v2[j];
#pragma unroll
        for (int j = 0; j < 8; j++) acc[j] += (float)v3[j];
    }
    for (; s < end; s += 4) {
        int u = srcs[s];
        bf16x8 v = *(const bf16x8*)(xb + (size_t)u * 128 + c * 8);
#pragma unroll
        for (int j = 0; j < 8; j++) acc[j] += (float)v[j];
    }
#pragma unroll
    for (int j = 0; j < 8; j++) {
        acc[j] += __shfl_xor(acc[j], 16, 64);
        acc[j] += __shfl_xor(acc[j], 32, 64);
    }
    float cnt = (float)(end - beg);
    if (cnt < 1.f) cnt = 1.f;
    if (grp == 0) {
        bf16x8 o;
#pragma unroll
        for (int j = 0; j < 8; j++) o[j] = (__bf16)(acc[j] / cnt);
        *(bf16x8*)(m1 + (size_t)n * 128 + c * 8) = o;
    }
}

// ---------------- fused GEMM1+GEMM2 ----------------
// Phase 1: h_tile = relu([m1|xb] @ W1T^T + b1)  -- kept in LDS (As, stride LDH)
// Phase 2: [Y|Z]  = h_tile @ W2T^T, staged in two K-halves through Bs (stride LDK)
// LDS: As 128x136 bf16 (34.8 KB) + Bs 128x72 (18.4 KB) = 53.2 KB
#define LDK 72   // Bs stride: 64-col staging tiles (+8 pad)
#define LDH 136  // As stride: fits the 128-col h tile (+8 pad), 16B-aligned rows

__global__ __launch_bounds__(256) void gemm12_kernel(const __bf16* __restrict__ A0,  // m1
                                                     const __bf16* __restrict__ A1,  // xb
                                                     const __bf16* __restrict__ W1T, // [128][256]
                                                     const __bf16* __restrict__ W2T, // [128][128]
                                                     const float* __restrict__ b1,
                                                     __bf16* __restrict__ Y,
                                                     float* __restrict__ Z, int M) {
    __shared__ __bf16 As[128 * LDH];
    __shared__ __bf16 Bs[128 * LDK];
    const int tid = threadIdx.x;
    const int row0 = blockIdx.x * 128;
    const int wave = tid >> 6, lane = tid & 63;
    const int wm = (wave & 1) * 64, wn = (wave >> 1) * 64;
    const int lr = lane & 15, quad = lane >> 4;

    // ---- phase 1: K=256 over [m1|xb] ----
    f32x4 acc[4][4] = {};
    for (int ks = 0; ks < 256; ks += 64) {
        const __bf16* Asrc = (ks < 128) ? A0 : A1;
        const int kofs = (ks < 128) ? ks : ks - 128;
        for (int i = tid; i < 128 * 8; i += 256) {
            int r = i >> 3, ch = i & 7;
            int gr = row0 + r;
            float4 v = {0.f, 0.f, 0.f, 0.f};
            if (gr < M) v = *(const float4*)(Asrc + (size_t)gr * 128 + kofs + ch * 8);
            *(float4*)(As + r * LDH + ch * 8) = v;
        }
        for (int i = tid; i < 128 * 8; i += 256) {
            int r = i >> 3, ch = i & 7;
            float4 v = *(const float4*)(W1T + (size_t)r * 256 + ks + ch * 8);
            *(float4*)(Bs + r * LDK + ch * 8) = v;
        }
        __syncthreads();
#pragma unroll
        for (int k0 = 0; k0 < 64; k0 += 32) {
            bf16x8 af[4], bfr[4];
#pragma unroll
            for (int mt = 0; mt < 4; mt++)
                af[mt] = *(const bf16x8*)(As + (wm + mt * 16 + lr) * LDH + k0 + quad * 8);
#pragma unroll
            for (int nt = 0; nt < 4; nt++)
                bfr[nt] = *(const bf16x8*)(Bs + (wn + nt * 16 + lr) * LDK + k0 + quad * 8);
#pragma unroll
            for (int mt = 0; mt < 4; mt++)
#pragma unroll
                for (int nt = 0; nt < 4; nt++)
                    acc[mt][nt] = __builtin_amdgcn_mfma_f32_16x16x32_bf16(af[mt], bfr[nt], acc[mt][nt], 0, 0, 0);
        }
        __syncthreads();
    }

    // ---- epilogue 1: h tile into As at stride LDH (bias+relu+bf16) ----
    // C/D layout: col = lane&15, row = quad*4 + reg. Waves write disjoint
    // 64x64 quadrants; the barrier inside the phase-2 loop orders reads.
#pragma unroll
    for (int mt = 0; mt < 4; mt++) {
#pragma unroll
        for (int r = 0; r < 4; r++) {
            int row = wm + mt * 16 + quad * 4 + r;
#pragma unroll
            for (int nt = 0; nt < 4; nt++) {
                int col = wn + nt * 16 + lr;
                float v = acc[mt][nt][r] + b1[col];
                v = v > 0.f ? v : 0.f;
                As[row * LDH + col] = (__bf16)v;
            }
        }
    }

    // ---- phase 2: K=128 over h tile, W2T staged in two 64-col halves ----
    f32x4 acc2[4][4] = {};
    for (int kh = 0; kh < 128; kh += 64) {
        for (int i = tid; i < 128 * 8; i += 256) {
            int r = i >> 3, ch = i & 7;
            float4 v = *(const float4*)(W2T + (size_t)r * 128 + kh + ch * 8);
            *(float4*)(Bs + r * LDK + ch * 8) = v;
        }
        __syncthreads();
#pragma unroll
        for (int k0 = 0; k0 < 64; k0 += 32) {
            bf16x8 af[4], bfr[4];
#pragma unroll
            for (int mt = 0; mt < 4; mt++)
                af[mt] = *(const bf16x8*)(As + (wm + mt * 16 + lr) * LDH + kh + k0 + quad * 8);
#pragma unroll
            for (int nt = 0; nt < 4; nt++)
                bfr[nt] = *(const bf16x8*)(Bs + (wn + nt * 16 + lr) * LDK + k0 + quad * 8);
#pragma unroll
            for (int mt = 0; mt < 4; mt++)
#pragma unroll
                for (int nt = 0; nt < 4; nt++)
                    acc2[mt][nt] = __builtin_amdgcn_mfma_f32_16x16x32_bf16(af[mt], bfr[nt], acc2[mt][nt], 0, 0, 0);
        }
        __syncthreads();
    }

    // ---- epilogue 2: Y bf16 / Z fp32 ----
#pragma unroll
    for (int mt = 0; mt < 4; mt++) {
#pragma unroll
        for (int r = 0; r < 4; r++) {
            int gr = row0 + wm + mt * 16 + quad * 4 + r;
            if (gr >= M) continue;
#pragma unroll
            for (int nt = 0; nt < 4; nt++) {
                int gc = wn + nt * 16 + lr;
                float v = acc2[mt][nt][r];
                if (gc < 64) Y[(size_t)gr * 64 + gc] = (__bf16)v;
                else         Z[(size_t)gr * 64 + (gc - 64)] = v;
            }
        }
    }
}

// ---------------- layer 2 aggregate + combine: out = mean(Y[src]) + b2 + Z ----------------
// one wave per node; 8 lanes cover a 128B Y row; 8 lane-groups x 2-deep
// unroll -> 16 loads in flight. Z/b2 loads hoisted to overlap latency.
__global__ __launch_bounds__(256) void agg2_kernel(const __bf16* __restrict__ Y,
                                                   const float* __restrict__ Z,
                                                   const int* __restrict__ row_ptr,
                                                   const int* __restrict__ srcs,
                                                   const float* __restrict__ b2,
                                                   float* __restrict__ out) {
    const int wid = threadIdx.x >> 6, lane = threadIdx.x & 63;
    const int n = blockIdx.x * 4 + wid;
    if (n >= N_NODES) return;
    const int beg = row_ptr[n], end = row_ptr[n + 1];
    const int grp = lane >> 3;  // edge slot 0..7
    const int c   = lane & 7;   // 16B chunk within row
    // hoist tail operands (only grp 0 consumes them)
    float4 z0 = {0,0,0,0}, z1 = {0,0,0,0}, bb0 = {0,0,0,0}, bb1 = {0,0,0,0};
    if (grp == 0) {
        z0 = *(const float4*)(Z + (size_t)n * 64 + c * 8);
        z1 = *(const float4*)(Z + (size_t)n * 64 + c * 8 + 4);
        bb0 = *(const float4*)(b2 + c * 8);
        bb1 = *(const float4*)(b2 + c * 8 + 4);
    }
    float acc[8] = {};
    int s = beg + grp;
    for (; s + 8 < end; s += 16) {
        int u0 = srcs[s];
        int u1 = srcs[s + 8];
        bf16x8 v0 = *(const bf16x8*)(Y + (size_t)u0 * 64 + c * 8);
        bf16x8 v1 = *(const bf16x8*)(Y + (size_t)u1 * 64 + c * 8);
#pragma unroll
        for (int j = 0; j < 8; j++) acc[j] += (float)v0[j];
#pragma unroll
        for (int j = 0; j < 8; j++) acc[j] += (float)v1[j];
    }
    if (s < end) {
        int u = srcs[s];
        bf16x8 v = *(const bf16x8*)(Y + (size_t)u * 64 + c * 8);
#pragma unroll
        for (int j = 0; j < 8; j++) acc[j] += (float)v[j];
    }
#pragma unroll
    for (int j = 0; j < 8; j++) {
        acc[j] += __shfl_xor(acc[j], 8, 64);
        acc[j] += __shfl_xor(acc[j], 16, 64);
        acc[j] += __shfl_xor(acc[j], 32, 64);
    }
    float cnt = (float)(end - beg);
    if (cnt < 1.f) cnt = 1.f;
    if (grp == 0) {
        float inv = 1.f / cnt;
        float4 o0 = { acc[0] * inv + bb0.x + z0.x, acc[1] * inv + bb0.y + z0.y,
                      acc[2] * inv + bb0.z + z0.z, acc[3] * inv + bb0.w + z0.w };
        float4 o1 = { acc[4] * inv + bb1.x + z1.x, acc[5] * inv + bb1.y + z1.y,
                      acc[6] * inv + bb1.z + z1.z, acc[7] * inv + bb1.w + z1.w };
        *(float4*)(out + (size_t)n * 64 + c * 8) = o0;
        *(float4*)(out + (size_t)n * 64 + c * 8 + 4) = o1;
    }
}

// ---------------- host ----------------

extern "C" void kernel_launch(void* const* d_in, const int* in_sizes, int n_in,
                              void* d_out, int out_size, void* d_ws, size_t ws_size,
                              hipStream_t stream) {
    const float* x   = (const float*)d_in[0];
    const int*   ei  = (const int*)d_in[1];
    const float* W1l = (const float*)d_in[2];
    const float* b1  = (const float*)d_in[3];
    const float* W1r = (const float*)d_in[4];
    const float* W2l = (const float*)d_in[5];
    const float* b2  = (const float*)d_in[6];
    const float* W2r = (const float*)d_in[7];
    float* out = (float*)d_out;

    // ---- workspace layout (~54 MB) with budget guard ----
    size_t need = 0;
    auto count = [&](size_t bytes) { need += (bytes + 255) & ~(size_t)255; };
    count((size_t)NBUCK * BCAP * 4);           // ebuf (packed uint32)
    count((size_t)NBUCK * CURS_STRIDE * 4);    // cursor (64B-padded)
    count((size_t)(N_NODES + 1) * 4);          // row_ptr
    count((size_t)N_EDGES * 4);                // srcs
    count((size_t)N_NODES * 128 * 2);          // xb
    count((size_t)128 * 256 * 2);              // W1T
    count((size_t)128 * 128 * 2);              // W2T
    count((size_t)N_NODES * 128 * 2);          // m1
    count((size_t)N_NODES * 64 * 2);           // Y
    count((size_t)N_NODES * 64 * 4);           // Z
    if (ws_size < need) return;

    char* ws = (char*)d_ws;
    size_t off = 0;
    auto alloc = [&](size_t bytes) -> void* {
        void* p = ws + off;
        off += (bytes + 255) & ~(size_t)255;
        return p;
    };
    unsigned* ebuf  = (unsigned*)alloc((size_t)NBUCK * BCAP * 4);
    int*    cursor  = (int*)alloc((size_t)NBUCK * CURS_STRIDE * 4);
    int*    row_ptr = (int*)alloc((size_t)(N_NODES + 1) * 4);
    int*    srcs    = (int*)alloc((size_t)N_EDGES * 4);
    __bf16* xb      = (__bf16*)alloc((size_t)N_NODES * 128 * 2);
    __bf16* W1T     = (__bf16*)alloc((size_t)128 * 256 * 2);
    __bf16* W2T     = (__bf16*)alloc((size_t)128 * 128 * 2);
    __bf16* m1      = (__bf16*)alloc((size_t)N_NODES * 128 * 2);
    __bf16* Y       = (__bf16*)alloc((size_t)N_NODES * 64 * 2);
    float*  Z       = (float*)alloc((size_t)N_NODES * 64 * 4);

    const int* src = ei;
    const int* dst = ei + N_EDGES;

    // 0. zero-init cursor (zero-based bucket counts; graph-capture-safe)
    hipMemsetAsync(cursor, 0, (size_t)NBUCK * CURS_STRIDE * 4, stream);
    // 1. fused prep + bucketA (bucketA blocks first: they feed the critical path)
    prep_bucketA_kernel<<<FUSED_BLOCKS, PB_THREADS, 0, stream>>>(x, W1l, W1r, W2l, W2r,
                                                                 xb, W1T, W2T,
                                                                 src, dst, cursor, ebuf);
    // 2. bucket CSR finalize
    bucketB_kernel<<<NBUCK, 256, 0, stream>>>(ebuf, cursor, row_ptr, srcs);
    // 3. layer-1 pre-aggregation
    agg_x_kernel<<<(N_NODES + 3) / 4, 256, 0, stream>>>(xb, row_ptr, srcs, m1);
    // 4. fused GEMM1(+bias+relu)+GEMM2
    gemm12_kernel<<<(N_NODES + 127) / 128, 256, 0, stream>>>(m1, xb, W1T, W2T, b1, Y, Z, N_NODES);
    // 5. layer-2 aggregate + combine
    agg2_kernel<<<(N_NODES + 3) / 4, 256, 0, stream>>>(Y, Z, row_ptr, srcs, b2, out);
}